// Round 10
// baseline (84.424 us; speedup 1.0000x reference)
//
#include <hip/hip_runtime.h>

#define D_C 128
#define BIN_SHIFT 9        // 512 rows per bin
#define BIN_CHUNK 4096     // edges per binA block
#define LBIN_CAP 96        // per-block per-bin LDS capacity
#define ROW_CAP 48         // per-row bucket capacity (mean 16, P(>48)~1e-11)

typedef __attribute__((ext_vector_type(8))) short bf16x8;
typedef __attribute__((ext_vector_type(4))) float f32x4;
typedef __attribute__((ext_vector_type(8))) unsigned short u16x8;

static __device__ __forceinline__ unsigned short f2bf(float f) {
    union { float f; unsigned u; } v; v.f = f;
    unsigned r = (v.u + 0x7FFFu + ((v.u >> 16) & 1u)) >> 16;  // RNE
    return (unsigned short)r;
}
static __device__ __forceinline__ float bf2f(unsigned short h) {
    union { unsigned u; float f; } v; v.u = ((unsigned)h) << 16;
    return v.f;
}

// ============================================================================
// PRIMARY: memset(gBinCnt) -> binA -> fused3   (R8 layout, R10 gather ILP)
// ws: gBinCnt[128] int | binStream[nBin*streamCap] u32 | xb[nN*128] u16
// Requires nN < 65536 (u16 row/col packing).
// ============================================================================

__global__ __launch_bounds__(256) void gcn_binA(
    const int* __restrict__ edge, const float* __restrict__ x,
    int* __restrict__ gBinCnt, unsigned* __restrict__ binStream,
    unsigned short* __restrict__ xb,
    int nE, int n8, int nN, int nBin, int streamCap)
{
    __shared__ unsigned lbin[128][LBIN_CAP];   // 48 KB
    __shared__ int lcnt[128];
    __shared__ int loff[128];

    const int t = threadIdx.x;
    if (t < 128) lcnt[t] = 0;
    __syncthreads();

    // --- bin this block's edge chunk into LDS ---
    const int e0  = blockIdx.x * BIN_CHUNK;
    const int eEnd = (e0 + BIN_CHUNK < nE) ? e0 + BIN_CHUNK : nE;
    for (int i = e0 + t; i < eEnd; i += 256) {
        const int r = edge[i];
        const int c = edge[nE + i];
        if ((unsigned)r < (unsigned)nN && (unsigned)c < (unsigned)nN) {
            const int bin = r >> BIN_SHIFT;
            const int s = atomicAdd(&lcnt[bin], 1);
            if (s < LBIN_CAP) lbin[bin][s] = ((unsigned)r << 16) | (unsigned)c;
        }
    }

    // --- x -> bf16 (independent streaming, hides under LDS binning) ---
    for (int i = blockIdx.x * 256 + t; i < n8; i += gridDim.x * 256) {
        const float4 a = ((const float4*)x)[2 * i];
        const float4 c = ((const float4*)x)[2 * i + 1];
        u16x8 pk;
        pk[0] = f2bf(a.x); pk[1] = f2bf(a.y); pk[2] = f2bf(a.z); pk[3] = f2bf(a.w);
        pk[4] = f2bf(c.x); pk[5] = f2bf(c.y); pk[6] = f2bf(c.z); pk[7] = f2bf(c.w);
        *(u16x8*)(xb + (size_t)i * 8) = pk;
    }
    __syncthreads();

    // --- reserve stream space: nBin lane-parallel atomics (1 round trip) ---
    if (t < nBin) {
        int n = lcnt[t]; if (n > LBIN_CAP) n = LBIN_CAP;
        lcnt[t] = n;
        loff[t] = atomicAdd(&gBinCnt[t], n);
    }
    __syncthreads();

    // --- coalesced flush: wave w handles bins w, w+4, ... ---
    const int wv = t >> 6, ln = t & 63;
    for (int bin = wv; bin < nBin; bin += 4) {
        const int n   = lcnt[bin];
        const int off = loff[bin];
        unsigned* dst = binStream + (size_t)bin * streamCap;
        for (int j = ln; j < n; j += 64)
            if (off + j < streamCap) dst[off + j] = lbin[bin][j];
    }
}

#define GLOAD(cc) (*(const u16x8*)(xb + (((size_t)(cc)) << 7) + cs * 8))

// Per-tile (128 rows): scan bin stream -> LDS row buckets -> gather (2 rows
// interleaved, 8 loads in flight per 16-lane group) -> MFMA + bias.
// 1024 thr = 16 waves; LDS 77K -> 2 blocks/CU.
__global__ __launch_bounds__(1024, 8) void gcn_fused3(
    const unsigned short* __restrict__ xb,
    const int* __restrict__ gBinCnt,
    const unsigned* __restrict__ binStream,
    const float* __restrict__ W,
    const float* __restrict__ b,
    float* __restrict__ out, int nN, int streamCap)
{
    __shared__ __align__(16) unsigned short w_s[128 * 128]; // 32 KB
    __shared__ __align__(16) unsigned short a_s[128 * 128]; // 32 KB
    __shared__ unsigned short lbuck[128 * ROW_CAP];         // 12 KB
    __shared__ int lcnt[128];

    const int t = threadIdx.x;

    // bijective XCD-chunked swizzle (m204): 4 tiles sharing a bin -> same XCD
    const int nT = gridDim.x;
    const int q = nT >> 3, r = nT & 7;
    const int xcd = blockIdx.x & 7, oj = blockIdx.x >> 3;
    const int lt = (xcd < r ? xcd * (q + 1) : r * (q + 1) + (xcd - r) * q) + oj;
    const int tile = lt << 7;              // first row of this 128-row tile
    const int bin  = lt >> 2;              // parent bin (512 rows = 4 tiles)

    if (t < 128) lcnt[t] = 0;

    // --- stage W: f32 -> bf16, swizzled (2 iters @ 1024 thr) ---
    for (int i = t * 8; i < 128 * 128; i += 1024 * 8) {
        const int n = i >> 7, k0 = i & 127;
        const float4 wa = *(const float4*)(W + i);
        const float4 wb = *(const float4*)(W + i + 4);
        u16x8 pk;
        pk[0] = f2bf(wa.x); pk[1] = f2bf(wa.y); pk[2] = f2bf(wa.z); pk[3] = f2bf(wa.w);
        pk[4] = f2bf(wb.x); pk[5] = f2bf(wb.y); pk[6] = f2bf(wb.z); pk[7] = f2bf(wb.w);
        *(u16x8*)&w_s[(n << 7) + (k0 ^ ((n & 15) << 3))] = pk;
    }
    __syncthreads();

    // --- scan parent bin stream, keep our 128 rows, bucket in LDS ---
    int n = gBinCnt[bin]; if (n > streamCap) n = streamCap;
    const unsigned* src = binStream + (size_t)bin * streamCap;
    for (int i = t; i < n; i += 1024) {
        const unsigned v = src[i];
        const int lr = (int)(v >> 16) - tile;
        if ((unsigned)lr < 128u) {
            const int s = atomicAdd(&lcnt[lr], 1);
            if (s < ROW_CAP) lbuck[lr * ROW_CAP + s] = (unsigned short)(v & 0xFFFFu);
        }
    }
    __syncthreads();

    // --- gather: 64 16-lane groups; group g owns rows 2g, 2g+1 INTERLEAVED ---
    {
        const int grp = t >> 4;       // 0..63
        const int cs  = t & 15;       // lane covers cols cs*8..cs*8+7
        const int iA = grp * 2, iB = grp * 2 + 1;
        const int dA = lcnt[iA],            dB = lcnt[iB];
        const int drA = (dA > ROW_CAP) ? ROW_CAP : dA;
        const int drB = (dB > ROW_CAP) ? ROW_CAP : dB;
        const unsigned short* bkA = &lbuck[iA * ROW_CAP];
        const unsigned short* bkB = &lbuck[iB * ROW_CAP];
        float accA[8] = {}, accB[8] = {};

        // joint 4-deep x 2 rows = 8 loads in flight
        const int m = ((drA < drB) ? drA : drB) & ~3;
        int e = 0;
        for (; e < m; e += 4) {
            const int a0 = bkA[e+0], a1 = bkA[e+1], a2 = bkA[e+2], a3 = bkA[e+3];
            const int b0 = bkB[e+0], b1 = bkB[e+1], b2 = bkB[e+2], b3 = bkB[e+3];
            const u16x8 vA0 = GLOAD(a0), vA1 = GLOAD(a1), vA2 = GLOAD(a2), vA3 = GLOAD(a3);
            const u16x8 vB0 = GLOAD(b0), vB1 = GLOAD(b1), vB2 = GLOAD(b2), vB3 = GLOAD(b3);
#pragma unroll
            for (int q2 = 0; q2 < 8; ++q2) {
                accA[q2] += (bf2f(vA0[q2]) + bf2f(vA1[q2])) + (bf2f(vA2[q2]) + bf2f(vA3[q2]));
                accB[q2] += (bf2f(vB0[q2]) + bf2f(vB1[q2])) + (bf2f(vB2[q2]) + bf2f(vB3[q2]));
            }
        }
        // remainders (typ. < 4 each)
        int eA = e;
        for (; eA + 4 <= drA; eA += 4) {
            const int a0 = bkA[eA+0], a1 = bkA[eA+1], a2 = bkA[eA+2], a3 = bkA[eA+3];
            const u16x8 v0 = GLOAD(a0), v1 = GLOAD(a1), v2 = GLOAD(a2), v3 = GLOAD(a3);
#pragma unroll
            for (int q2 = 0; q2 < 8; ++q2)
                accA[q2] += (bf2f(v0[q2]) + bf2f(v1[q2])) + (bf2f(v2[q2]) + bf2f(v3[q2]));
        }
        for (; eA < drA; ++eA) {
            const u16x8 v0 = GLOAD(bkA[eA]);
#pragma unroll
            for (int q2 = 0; q2 < 8; ++q2) accA[q2] += bf2f(v0[q2]);
        }
        int eB = e;
        for (; eB + 4 <= drB; eB += 4) {
            const int b0 = bkB[eB+0], b1 = bkB[eB+1], b2 = bkB[eB+2], b3 = bkB[eB+3];
            const u16x8 v0 = GLOAD(b0), v1 = GLOAD(b1), v2 = GLOAD(b2), v3 = GLOAD(b3);
#pragma unroll
            for (int q2 = 0; q2 < 8; ++q2)
                accB[q2] += (bf2f(v0[q2]) + bf2f(v1[q2])) + (bf2f(v2[q2]) + bf2f(v3[q2]));
        }
        for (; eB < drB; ++eB) {
            const u16x8 v0 = GLOAD(bkB[eB]);
#pragma unroll
            for (int q2 = 0; q2 < 8; ++q2) accB[q2] += bf2f(v0[q2]);
        }

        const float invA = (dA > 0) ? 1.0f / (float)dA : 0.0f;
        const float invB = (dB > 0) ? 1.0f / (float)dB : 0.0f;
        u16x8 pkA, pkB;
#pragma unroll
        for (int q2 = 0; q2 < 8; ++q2) {
            pkA[q2] = f2bf(accA[q2] * invA);
            pkB[q2] = f2bf(accB[q2] * invB);
        }
        *(u16x8*)&a_s[(iA << 7) + ((cs * 8) ^ ((iA & 15) << 3))] = pkA;
        *(u16x8*)&a_s[(iB << 7) + ((cs * 8) ^ ((iB & 15) << 3))] = pkB;
    }
    __syncthreads();

    // --- MFMA: wave w -> rows (w>>1)*16..+15, cols (w&1)*64..+63 ---
    const int l    = t & 63;
    const int w    = t >> 6;      // 0..15
    const int strip = w >> 1;     // 0..7
    const int half  = w & 1;      // 0..1
    const int lr = l & 15;
    const int lg = l >> 4;

    float bv[4];
#pragma unroll
    for (int nt = 0; nt < 4; ++nt) bv[nt] = b[half * 64 + nt * 16 + lr];

    f32x4 acc[4] = {};
    const int ar = strip * 16 + lr;
    const int abase = ar << 7;
    const int asw = (ar & 15) << 3;
#pragma unroll
    for (int kk = 0; kk < 4; ++kk) {
        const int k = kk * 32 + lg * 8;
        const bf16x8 af = *(const bf16x8*)&a_s[abase + (k ^ asw)];
#pragma unroll
        for (int nt = 0; nt < 4; ++nt) {
            const int br = half * 64 + nt * 16 + lr;
            const bf16x8 bf = *(const bf16x8*)&w_s[(br << 7) + (k ^ ((br & 15) << 3))];
            acc[nt] = __builtin_amdgcn_mfma_f32_16x16x32_bf16(af, bf, acc[nt], 0, 0, 0);
        }
    }

    // C/D: col = lane&15, row = (lane>>4)*4 + reg  (m89-verified)
#pragma unroll
    for (int nt = 0; nt < 4; ++nt) {
#pragma unroll
        for (int j = 0; j < 4; ++j) {
            const int row = tile + strip * 16 + lg * 4 + j;
            if (row < nN)
                out[(size_t)row * 128 + half * 64 + nt * 16 + lr] = acc[nt][j] + bv[nt];
        }
    }
}

// ============================================================================
// FALLBACK: atomic path (ws too small / nN too large for u16 packing)
// ============================================================================
__global__ void gcn_scatter(const int* __restrict__ edge,
                            const float* __restrict__ x,
                            float* __restrict__ agg,
                            float* __restrict__ deg, int nE, int nN) {
    const int lane  = threadIdx.x & 63;
    const int wave  = (blockIdx.x * blockDim.x + threadIdx.x) >> 6;
    const int nWave = (gridDim.x * blockDim.x) >> 6;
    for (int e = wave; e < nE; e += nWave) {
        int r = edge[e];
        int c = edge[nE + e];
        if ((unsigned)r >= (unsigned)nN || (unsigned)c >= (unsigned)nN) continue;
        const float2 v = ((const float2*)(x + (size_t)c * D_C))[lane];
        float* op = agg + (size_t)r * D_C + 2 * lane;
        atomicAdd(op, v.x);
        atomicAdd(op + 1, v.y);
        if (lane == 0) atomicAdd(deg + r, 1.0f);
    }
}

__global__ void gcn_mm(float* __restrict__ io, const float* __restrict__ deg,
                       const float* __restrict__ W, const float* __restrict__ b,
                       int nN) {
    __shared__ float a[D_C];
    const int c = threadIdx.x;
    const float bias = b[c];
    const float4* __restrict__ w4 = (const float4*)(W + (size_t)c * D_C);
    for (int r = blockIdx.x; r < nN; r += gridDim.x) {
        const float inv = 1.0f / deg[r];
        a[c] = io[(size_t)r * D_C + c] * inv;
        __syncthreads();
        float acc = bias;
        const float4* a4 = (const float4*)a;
#pragma unroll
        for (int k = 0; k < D_C / 4; ++k) {
            const float4 wv = w4[k];
            const float4 av = a4[k];
            acc = fmaf(wv.x, av.x, acc);
            acc = fmaf(wv.y, av.y, acc);
            acc = fmaf(wv.z, av.z, acc);
            acc = fmaf(wv.w, av.w, acc);
        }
        __syncthreads();
        io[(size_t)r * D_C + c] = acc;
    }
}

extern "C" void kernel_launch(void* const* d_in, const int* in_sizes, int n_in,
                              void* d_out, int out_size, void* d_ws, size_t ws_size,
                              hipStream_t stream) {
    const float* x    = (const float*)d_in[0];
    const int*   edge = (const int*)  d_in[1];
    const float* W    = (const float*)d_in[2];
    const float* b    = (const float*)d_in[3];

    const int nN = in_sizes[0] / D_C;   // 50000
    const int nE = in_sizes[1] / 2;     // 800000
    const int n8 = nN * D_C / 8;

    const int nBin = (nN + (1 << BIN_SHIFT) - 1) >> BIN_SHIFT;          // 98
    const int streamCap = ((nE / nBin) + 1024 + 3) & ~3;                // ~9188
    const size_t need = 128 * sizeof(int)
                      + (size_t)nBin * streamCap * sizeof(unsigned)
                      + (size_t)nN * D_C * sizeof(unsigned short);

    if (nN < 65536 && nBin <= 128 && ws_size >= need) {
        int* gBinCnt = (int*)d_ws;
        unsigned* binStream = (unsigned*)(gBinCnt + 128);
        unsigned short* xb = (unsigned short*)(binStream + (size_t)nBin * streamCap);

        hipMemsetAsync(gBinCnt, 0, 128 * sizeof(int), stream);
        const int nBlkA = (nE + BIN_CHUNK - 1) / BIN_CHUNK;             // 196
        gcn_binA<<<nBlkA, 256, 0, stream>>>(edge, x, gBinCnt, binStream, xb,
                                            nE, n8, nN, nBin, streamCap);
        const int nT = (nN + 127) / 128;                                // 391
        gcn_fused3<<<nT, 1024, 0, stream>>>(xb, gBinCnt, binStream, W, b,
                                            (float*)d_out, nN, streamCap);
    } else {
        float* agg = (float*)d_out;
        float* deg = (float*)d_ws;
        hipMemsetAsync(agg, 0, (size_t)out_size * sizeof(float), stream);
        hipMemsetAsync(deg, 0, (size_t)nN * sizeof(float), stream);
        gcn_scatter<<<2048, 256, 0, stream>>>(edge, x, agg, deg, nE, nN);
        gcn_mm<<<nN, 128, 0, stream>>>(agg, deg, W, b, nN);
    }
}

// Round 11
// 72.911 us; speedup vs baseline: 1.1579x; 1.1579x over previous
//
#include <hip/hip_runtime.h>

#define D_C 128
#define BIN_SHIFT 9        // 512 rows per bin
#define BIN_CHUNK 2048     // edges per binA block (391 blocks -> fills CUs)
#define LBIN_CAP 64        // per-block per-bin LDS cap (mean 21, +9 sigma)
#define ROW_CAP 48         // per-row bucket capacity (mean 16, P(>48)~1e-11)

typedef __attribute__((ext_vector_type(8))) short bf16x8;
typedef __attribute__((ext_vector_type(4))) float f32x4;
typedef __attribute__((ext_vector_type(8))) unsigned short u16x8;

static __device__ __forceinline__ unsigned short f2bf(float f) {
    union { float f; unsigned u; } v; v.f = f;
    unsigned r = (v.u + 0x7FFFu + ((v.u >> 16) & 1u)) >> 16;  // RNE
    return (unsigned short)r;
}
static __device__ __forceinline__ float bf2f(unsigned short h) {
    union { unsigned u; float f; } v; v.u = ((unsigned)h) << 16;
    return v.f;
}

// ============================================================================
// PRIMARY: memset(gBinCnt) -> binA -> fused3
// ws: gBinCnt[128] int | binStream[nBin*streamCap] u32 | xb[nN*128] u16
// Requires nN < 65536 (u16 row/col packing).
// ============================================================================

__global__ __launch_bounds__(256) void gcn_binA(
    const int* __restrict__ edge, const float* __restrict__ x,
    int* __restrict__ gBinCnt, unsigned* __restrict__ binStream,
    unsigned short* __restrict__ xb,
    int nE, int n8, int nN, int nBin, int streamCap)
{
    __shared__ unsigned lbin[128][LBIN_CAP];   // 32 KB
    __shared__ int lcnt[128];
    __shared__ int loff[128];

    const int t = threadIdx.x;
    if (t < 128) lcnt[t] = 0;
    __syncthreads();

    // --- bin this block's edge chunk into LDS ---
    const int e0  = blockIdx.x * BIN_CHUNK;
    const int eEnd = (e0 + BIN_CHUNK < nE) ? e0 + BIN_CHUNK : nE;
    for (int i = e0 + t; i < eEnd; i += 256) {
        const int r = edge[i];
        const int c = edge[nE + i];
        if ((unsigned)r < (unsigned)nN && (unsigned)c < (unsigned)nN) {
            const int bin = r >> BIN_SHIFT;
            const int s = atomicAdd(&lcnt[bin], 1);
            if (s < LBIN_CAP) lbin[bin][s] = ((unsigned)r << 16) | (unsigned)c;
        }
    }

    // --- x -> bf16 (independent streaming, hides under LDS binning) ---
    for (int i = blockIdx.x * 256 + t; i < n8; i += gridDim.x * 256) {
        const float4 a = ((const float4*)x)[2 * i];
        const float4 c = ((const float4*)x)[2 * i + 1];
        u16x8 pk;
        pk[0] = f2bf(a.x); pk[1] = f2bf(a.y); pk[2] = f2bf(a.z); pk[3] = f2bf(a.w);
        pk[4] = f2bf(c.x); pk[5] = f2bf(c.y); pk[6] = f2bf(c.z); pk[7] = f2bf(c.w);
        *(u16x8*)(xb + (size_t)i * 8) = pk;
    }
    __syncthreads();

    // --- reserve stream space: nBin lane-parallel atomics (1 round trip) ---
    if (t < nBin) {
        int n = lcnt[t]; if (n > LBIN_CAP) n = LBIN_CAP;
        lcnt[t] = n;
        loff[t] = atomicAdd(&gBinCnt[t], n);
    }
    __syncthreads();

    // --- coalesced flush: wave w handles bins w, w+4, ... ---
    const int wv = t >> 6, ln = t & 63;
    for (int bin = wv; bin < nBin; bin += 4) {
        const int n   = lcnt[bin];
        const int off = loff[bin];
        unsigned* dst = binStream + (size_t)bin * streamCap;
        for (int j = ln; j < n; j += 64)
            if (off + j < streamCap) dst[off + j] = lbin[bin][j];
    }
}

#define GLOAD(cc) (*(const u16x8*)(xb + (((size_t)(cc)) << 7) + cs * 8))

// Per-tile (128 rows): scan bin stream -> LDS row buckets -> gather (6-deep
// MLP, single row per 16-lane group) -> MFMA + bias.
// 1024 thr = 16 waves; LDS 77K -> 2 blocks/CU; VGPR budget ~48 < 64 cap.
__global__ __launch_bounds__(1024, 8) void gcn_fused3(
    const unsigned short* __restrict__ xb,
    const int* __restrict__ gBinCnt,
    const unsigned* __restrict__ binStream,
    const float* __restrict__ W,
    const float* __restrict__ b,
    float* __restrict__ out, int nN, int streamCap)
{
    __shared__ __align__(16) unsigned short w_s[128 * 128]; // 32 KB
    __shared__ __align__(16) unsigned short a_s[128 * 128]; // 32 KB
    __shared__ unsigned short lbuck[128 * ROW_CAP];         // 12 KB
    __shared__ int lcnt[128];

    const int t = threadIdx.x;

    // bijective XCD-chunked swizzle (m204): 4 tiles sharing a bin -> same XCD
    const int nT = gridDim.x;
    const int q = nT >> 3, r = nT & 7;
    const int xcd = blockIdx.x & 7, oj = blockIdx.x >> 3;
    const int lt = (xcd < r ? xcd * (q + 1) : r * (q + 1) + (xcd - r) * q) + oj;
    const int tile = lt << 7;              // first row of this 128-row tile
    const int bin  = lt >> 2;              // parent bin (512 rows = 4 tiles)

    if (t < 128) lcnt[t] = 0;

    // --- stage W: f32 -> bf16, swizzled (2 iters @ 1024 thr) ---
    for (int i = t * 8; i < 128 * 128; i += 1024 * 8) {
        const int n = i >> 7, k0 = i & 127;
        const float4 wa = *(const float4*)(W + i);
        const float4 wb = *(const float4*)(W + i + 4);
        u16x8 pk;
        pk[0] = f2bf(wa.x); pk[1] = f2bf(wa.y); pk[2] = f2bf(wa.z); pk[3] = f2bf(wa.w);
        pk[4] = f2bf(wb.x); pk[5] = f2bf(wb.y); pk[6] = f2bf(wb.z); pk[7] = f2bf(wb.w);
        *(u16x8*)&w_s[(n << 7) + (k0 ^ ((n & 15) << 3))] = pk;
    }
    __syncthreads();

    // --- scan parent bin stream, keep our 128 rows, bucket in LDS ---
    int n = gBinCnt[bin]; if (n > streamCap) n = streamCap;
    const unsigned* src = binStream + (size_t)bin * streamCap;
    for (int i = t; i < n; i += 1024) {
        const unsigned v = src[i];
        const int lr = (int)(v >> 16) - tile;
        if ((unsigned)lr < 128u) {
            const int s = atomicAdd(&lcnt[lr], 1);
            if (s < ROW_CAP) lbuck[lr * ROW_CAP + s] = (unsigned short)(v & 0xFFFFu);
        }
    }
    __syncthreads();

    // --- gather: 64 16-lane groups, group g -> rows 2g, 2g+1 (6-deep MLP) ---
    {
        const int grp = t >> 4;       // 0..63
        const int cs  = t & 15;       // lane covers cols cs*8..cs*8+7
        for (int jj = 0; jj < 2; ++jj) {
            const int i = grp * 2 + jj;          // row in tile
            float acc[8] = {};
            const int d  = lcnt[i];
            const int dr = (d > ROW_CAP) ? ROW_CAP : d;
            const unsigned short* bk = &lbuck[i * ROW_CAP];
            int e = 0;
            for (; e + 6 <= dr; e += 6) {        // 6 loads in flight
                const int c0 = bk[e + 0];
                const int c1 = bk[e + 1];
                const int c2 = bk[e + 2];
                const int c3 = bk[e + 3];
                const int c4 = bk[e + 4];
                const int c5 = bk[e + 5];
                const u16x8 v0 = GLOAD(c0), v1 = GLOAD(c1), v2 = GLOAD(c2);
                const u16x8 v3 = GLOAD(c3), v4 = GLOAD(c4), v5 = GLOAD(c5);
#pragma unroll
                for (int q2 = 0; q2 < 8; ++q2)
                    acc[q2] += ((bf2f(v0[q2]) + bf2f(v1[q2]))
                              + (bf2f(v2[q2]) + bf2f(v3[q2])))
                              + (bf2f(v4[q2]) + bf2f(v5[q2]));
            }
            for (; e + 2 <= dr; e += 2) {
                const int c0 = bk[e + 0];
                const int c1 = bk[e + 1];
                const u16x8 v0 = GLOAD(c0), v1 = GLOAD(c1);
#pragma unroll
                for (int q2 = 0; q2 < 8; ++q2)
                    acc[q2] += bf2f(v0[q2]) + bf2f(v1[q2]);
            }
            if (e < dr) {
                const u16x8 v0 = GLOAD(bk[e]);
#pragma unroll
                for (int q2 = 0; q2 < 8; ++q2) acc[q2] += bf2f(v0[q2]);
            }
            const float inv = (d > 0) ? 1.0f / (float)d : 0.0f;
            u16x8 pk;
#pragma unroll
            for (int q2 = 0; q2 < 8; ++q2) pk[q2] = f2bf(acc[q2] * inv);
            *(u16x8*)&a_s[(i << 7) + ((cs * 8) ^ ((i & 15) << 3))] = pk;
        }
    }
    __syncthreads();

    // --- MFMA: wave w -> rows (w>>1)*16..+15, cols (w&1)*64..+63 ---
    const int l    = t & 63;
    const int w    = t >> 6;      // 0..15
    const int strip = w >> 1;     // 0..7
    const int half  = w & 1;      // 0..1
    const int lr = l & 15;
    const int lg = l >> 4;

    float bv[4];
#pragma unroll
    for (int nt = 0; nt < 4; ++nt) bv[nt] = b[half * 64 + nt * 16 + lr];

    f32x4 acc[4] = {};
    const int ar = strip * 16 + lr;
    const int abase = ar << 7;
    const int asw = (ar & 15) << 3;
#pragma unroll
    for (int kk = 0; kk < 4; ++kk) {
        const int k = kk * 32 + lg * 8;
        const bf16x8 af = *(const bf16x8*)&a_s[abase + (k ^ asw)];
#pragma unroll
        for (int nt = 0; nt < 4; ++nt) {
            const int br = half * 64 + nt * 16 + lr;
            const bf16x8 bf = *(const bf16x8*)&w_s[(br << 7) + (k ^ ((br & 15) << 3))];
            acc[nt] = __builtin_amdgcn_mfma_f32_16x16x32_bf16(af, bf, acc[nt], 0, 0, 0);
        }
    }

    // C/D: col = lane&15, row = (lane>>4)*4 + reg  (m89-verified)
#pragma unroll
    for (int nt = 0; nt < 4; ++nt) {
#pragma unroll
        for (int j = 0; j < 4; ++j) {
            const int row = tile + strip * 16 + lg * 4 + j;
            if (row < nN)
                out[(size_t)row * 128 + half * 64 + nt * 16 + lr] = acc[nt][j] + bv[nt];
        }
    }
}

// ============================================================================
// FALLBACK: atomic path (ws too small / nN too large for u16 packing)
// ============================================================================
__global__ void gcn_scatter(const int* __restrict__ edge,
                            const float* __restrict__ x,
                            float* __restrict__ agg,
                            float* __restrict__ deg, int nE, int nN) {
    const int lane  = threadIdx.x & 63;
    const int wave  = (blockIdx.x * blockDim.x + threadIdx.x) >> 6;
    const int nWave = (gridDim.x * blockDim.x) >> 6;
    for (int e = wave; e < nE; e += nWave) {
        int r = edge[e];
        int c = edge[nE + e];
        if ((unsigned)r >= (unsigned)nN || (unsigned)c >= (unsigned)nN) continue;
        const float2 v = ((const float2*)(x + (size_t)c * D_C))[lane];
        float* op = agg + (size_t)r * D_C + 2 * lane;
        atomicAdd(op, v.x);
        atomicAdd(op + 1, v.y);
        if (lane == 0) atomicAdd(deg + r, 1.0f);
    }
}

__global__ void gcn_mm(float* __restrict__ io, const float* __restrict__ deg,
                       const float* __restrict__ W, const float* __restrict__ b,
                       int nN) {
    __shared__ float a[D_C];
    const int c = threadIdx.x;
    const float bias = b[c];
    const float4* __restrict__ w4 = (const float4*)(W + (size_t)c * D_C);
    for (int r = blockIdx.x; r < nN; r += gridDim.x) {
        const float inv = 1.0f / deg[r];
        a[c] = io[(size_t)r * D_C + c] * inv;
        __syncthreads();
        float acc = bias;
        const float4* a4 = (const float4*)a;
#pragma unroll
        for (int k = 0; k < D_C / 4; ++k) {
            const float4 wv = w4[k];
            const float4 av = a4[k];
            acc = fmaf(wv.x, av.x, acc);
            acc = fmaf(wv.y, av.y, acc);
            acc = fmaf(wv.z, av.z, acc);
            acc = fmaf(wv.w, av.w, acc);
        }
        __syncthreads();
        io[(size_t)r * D_C + c] = acc;
    }
}

extern "C" void kernel_launch(void* const* d_in, const int* in_sizes, int n_in,
                              void* d_out, int out_size, void* d_ws, size_t ws_size,
                              hipStream_t stream) {
    const float* x    = (const float*)d_in[0];
    const int*   edge = (const int*)  d_in[1];
    const float* W    = (const float*)d_in[2];
    const float* b    = (const float*)d_in[3];

    const int nN = in_sizes[0] / D_C;   // 50000
    const int nE = in_sizes[1] / 2;     // 800000
    const int n8 = nN * D_C / 8;

    const int nBin = (nN + (1 << BIN_SHIFT) - 1) >> BIN_SHIFT;          // 98
    const int streamCap = ((nE / nBin) + 1024 + 3) & ~3;                // ~9188
    const size_t need = 128 * sizeof(int)
                      + (size_t)nBin * streamCap * sizeof(unsigned)
                      + (size_t)nN * D_C * sizeof(unsigned short);

    if (nN < 65536 && nBin <= 128 && ws_size >= need) {
        int* gBinCnt = (int*)d_ws;
        unsigned* binStream = (unsigned*)(gBinCnt + 128);
        unsigned short* xb = (unsigned short*)(binStream + (size_t)nBin * streamCap);

        hipMemsetAsync(gBinCnt, 0, 128 * sizeof(int), stream);
        const int nBlkA = (nE + BIN_CHUNK - 1) / BIN_CHUNK;             // 391
        gcn_binA<<<nBlkA, 256, 0, stream>>>(edge, x, gBinCnt, binStream, xb,
                                            nE, n8, nN, nBin, streamCap);
        const int nT = (nN + 127) / 128;                                // 391
        gcn_fused3<<<nT, 1024, 0, stream>>>(xb, gBinCnt, binStream, W, b,
                                            (float*)d_out, nN, streamCap);
    } else {
        float* agg = (float*)d_out;
        float* deg = (float*)d_ws;
        hipMemsetAsync(agg, 0, (size_t)out_size * sizeof(float), stream);
        hipMemsetAsync(deg, 0, (size_t)nN * sizeof(float), stream);
        gcn_scatter<<<2048, 256, 0, stream>>>(edge, x, agg, deg, nE, nN);
        gcn_mm<<<nN, 128, 0, stream>>>(agg, deg, W, b, nN);
    }
}

// Round 12
// 54.650 us; speedup vs baseline: 1.5448x; 1.3341x over previous
//
#include <hip/hip_runtime.h>

#define D_C 128
#define BIN_SHIFT 9        // 512 rows per bin
#define BIN_CHUNK 2048     // edges per binA block
#define SEG_W 64           // segment: word0=count, words 1..63 = entries (256 B)
#define ROW_CAP 48         // per-row bucket capacity (mean 16, P(>48)~1e-11)

typedef __attribute__((ext_vector_type(8))) short bf16x8;
typedef __attribute__((ext_vector_type(4))) float f32x4;
typedef __attribute__((ext_vector_type(8))) unsigned short u16x8;

static __device__ __forceinline__ unsigned short f2bf(float f) {
    union { float f; unsigned u; } v; v.f = f;
    unsigned r = (v.u + 0x7FFFu + ((v.u >> 16) & 1u)) >> 16;  // RNE
    return (unsigned short)r;
}
static __device__ __forceinline__ float bf2f(unsigned short h) {
    union { unsigned u; float f; } v; v.u = ((unsigned)h) << 16;
    return v.f;
}

// ============================================================================
// PRIMARY: cvt -> binA -> fused3   (no global atomics, no memset)
// ws: seg[nBin][nBlkA][SEG_W] u32 | xb[nN*128] u16
// Requires nN < 65536 (u16 row/col packing).
// ============================================================================

// x -> bf16, pure streaming
__global__ void gcn_cvt(const float* __restrict__ x,
                        unsigned short* __restrict__ xb, int n8) {
    int i = blockIdx.x * blockDim.x + threadIdx.x;
    if (i < n8) {
        const float4 a = ((const float4*)x)[2 * i];
        const float4 c = ((const float4*)x)[2 * i + 1];
        u16x8 pk;
        pk[0] = f2bf(a.x); pk[1] = f2bf(a.y); pk[2] = f2bf(a.z); pk[3] = f2bf(a.w);
        pk[4] = f2bf(c.x); pk[5] = f2bf(c.y); pk[6] = f2bf(c.z); pk[7] = f2bf(c.w);
        *(u16x8*)(xb + (size_t)i * 8) = pk;
    }
}

// Bin this block's edge chunk into LDS, then flush each bin as ONE 64-lane
// full-line store into the block's PRIVATE segment. Zero global atomics.
__global__ __launch_bounds__(256) void gcn_binA(
    const int* __restrict__ edge, unsigned* __restrict__ seg,
    int nE, int nN, int nBin, int nBlkA)
{
    __shared__ unsigned lbin[128][SEG_W];   // 32 KB; [bin][0]=count later
    __shared__ int lcnt[128];

    const int t = threadIdx.x;
    if (t < 128) lcnt[t] = 0;
    __syncthreads();

    const int e0   = blockIdx.x * BIN_CHUNK;
    const int eEnd = (e0 + BIN_CHUNK < nE) ? e0 + BIN_CHUNK : nE;
    for (int i = e0 + t; i < eEnd; i += 256) {
        const int r = edge[i];
        const int c = edge[nE + i];
        if ((unsigned)r < (unsigned)nN && (unsigned)c < (unsigned)nN) {
            const int bin = r >> BIN_SHIFT;
            const int s = atomicAdd(&lcnt[bin], 1);     // LDS atomic only
            if (s < SEG_W - 1) lbin[bin][1 + s] = ((unsigned)r << 16) | (unsigned)c;
        }
    }
    __syncthreads();
    if (t < 128) {
        int n = lcnt[t]; if (n > SEG_W - 1) n = SEG_W - 1;
        lbin[t][0] = (unsigned)n;
    }
    __syncthreads();

    // flush: wave wv -> bins wv, wv+4, ...; one 256B full-line store per bin
    const int wv = t >> 6, ln = t & 63;
    for (int bin = wv; bin < nBin; bin += 4) {
        unsigned* dst = seg + (((size_t)bin * nBlkA) + blockIdx.x) * SEG_W;
        dst[ln] = lbin[bin][ln];   // slots beyond count carry unused data
    }
}

#define GLOAD(cc) (*(const u16x8*)(xb + (((size_t)(cc)) << 7) + cs * 8))

// Per-tile (128 rows): scan private segments of parent bin -> LDS row
// buckets -> gather (6-deep MLP) -> MFMA + bias.
// 1024 thr = 16 waves; LDS 77K -> 2 blocks/CU; VGPR ~48 < 64 cap.
__global__ __launch_bounds__(1024, 8) void gcn_fused3(
    const unsigned short* __restrict__ xb,
    const unsigned* __restrict__ seg,
    const float* __restrict__ W,
    const float* __restrict__ b,
    float* __restrict__ out, int nN, int nBlkA)
{
    __shared__ __align__(16) unsigned short w_s[128 * 128]; // 32 KB
    __shared__ __align__(16) unsigned short a_s[128 * 128]; // 32 KB
    __shared__ unsigned short lbuck[128 * ROW_CAP];         // 12 KB
    __shared__ int lcnt[128];

    const int t = threadIdx.x;
    const int l = t & 63;

    // bijective XCD-chunked swizzle (m204): 4 tiles sharing a bin -> same XCD
    const int nT = gridDim.x;
    const int q = nT >> 3, r = nT & 7;
    const int xcd = blockIdx.x & 7, oj = blockIdx.x >> 3;
    const int lt = (xcd < r ? xcd * (q + 1) : r * (q + 1) + (xcd - r) * q) + oj;
    const int tile = lt << 7;              // first row of this 128-row tile
    const int bin  = lt >> 2;              // parent bin (512 rows = 4 tiles)

    if (t < 128) lcnt[t] = 0;

    // --- stage W: f32 -> bf16, swizzled (2 iters @ 1024 thr) ---
    for (int i = t * 8; i < 128 * 128; i += 1024 * 8) {
        const int n = i >> 7, k0 = i & 127;
        const float4 wa = *(const float4*)(W + i);
        const float4 wb = *(const float4*)(W + i + 4);
        u16x8 pk;
        pk[0] = f2bf(wa.x); pk[1] = f2bf(wa.y); pk[2] = f2bf(wa.z); pk[3] = f2bf(wa.w);
        pk[4] = f2bf(wb.x); pk[5] = f2bf(wb.y); pk[6] = f2bf(wb.z); pk[7] = f2bf(wb.w);
        *(u16x8*)&w_s[(n << 7) + (k0 ^ ((n & 15) << 3))] = pk;
    }
    __syncthreads();

    // --- scan private segments: 16-lane group per segment ---
    {
        const int grp = t >> 4;       // 0..63
        const int cs  = t & 15;
        const unsigned* segb = seg + (size_t)bin * nBlkA * SEG_W;
        for (int s = grp; s < nBlkA; s += 64) {
            const unsigned* sp = segb + (size_t)s * SEG_W;
            const unsigned w0 = sp[cs];                     // word cs (0..15)
            const int n = (int)__shfl(w0, l & 48, 64);      // count from lane0 of group
            if (cs >= 1 && cs <= n) {
                const int lr = (int)(w0 >> 16) - tile;
                if ((unsigned)lr < 128u) {
                    const int sl = atomicAdd(&lcnt[lr], 1);
                    if (sl < ROW_CAP) lbuck[lr * ROW_CAP + sl] = (unsigned short)(w0 & 0xFFFFu);
                }
            }
            for (int j = 16 + cs; j <= n; j += 16) {
                const unsigned v = sp[j];
                const int lr = (int)(v >> 16) - tile;
                if ((unsigned)lr < 128u) {
                    const int sl = atomicAdd(&lcnt[lr], 1);
                    if (sl < ROW_CAP) lbuck[lr * ROW_CAP + sl] = (unsigned short)(v & 0xFFFFu);
                }
            }
        }
    }
    __syncthreads();

    // --- gather: 64 16-lane groups, group g -> rows 2g, 2g+1 (6-deep MLP) ---
    {
        const int grp = t >> 4;       // 0..63
        const int cs  = t & 15;       // lane covers cols cs*8..cs*8+7
        for (int jj = 0; jj < 2; ++jj) {
            const int i = grp * 2 + jj;          // row in tile
            float acc[8] = {};
            const int d  = lcnt[i];
            const int dr = (d > ROW_CAP) ? ROW_CAP : d;
            const unsigned short* bk = &lbuck[i * ROW_CAP];
            int e = 0;
            for (; e + 6 <= dr; e += 6) {        // 6 loads in flight
                const int c0 = bk[e + 0];
                const int c1 = bk[e + 1];
                const int c2 = bk[e + 2];
                const int c3 = bk[e + 3];
                const int c4 = bk[e + 4];
                const int c5 = bk[e + 5];
                const u16x8 v0 = GLOAD(c0), v1 = GLOAD(c1), v2 = GLOAD(c2);
                const u16x8 v3 = GLOAD(c3), v4 = GLOAD(c4), v5 = GLOAD(c5);
#pragma unroll
                for (int q2 = 0; q2 < 8; ++q2)
                    acc[q2] += ((bf2f(v0[q2]) + bf2f(v1[q2]))
                              + (bf2f(v2[q2]) + bf2f(v3[q2])))
                              + (bf2f(v4[q2]) + bf2f(v5[q2]));
            }
            for (; e + 2 <= dr; e += 2) {
                const int c0 = bk[e + 0];
                const int c1 = bk[e + 1];
                const u16x8 v0 = GLOAD(c0), v1 = GLOAD(c1);
#pragma unroll
                for (int q2 = 0; q2 < 8; ++q2)
                    acc[q2] += bf2f(v0[q2]) + bf2f(v1[q2]);
            }
            if (e < dr) {
                const u16x8 v0 = GLOAD(bk[e]);
#pragma unroll
                for (int q2 = 0; q2 < 8; ++q2) acc[q2] += bf2f(v0[q2]);
            }
            const float inv = (d > 0) ? 1.0f / (float)d : 0.0f;
            u16x8 pk;
#pragma unroll
            for (int q2 = 0; q2 < 8; ++q2) pk[q2] = f2bf(acc[q2] * inv);
            *(u16x8*)&a_s[(i << 7) + ((cs * 8) ^ ((i & 15) << 3))] = pk;
        }
    }
    __syncthreads();

    // --- MFMA: wave w -> rows (w>>1)*16..+15, cols (w&1)*64..+63 ---
    const int w    = t >> 6;      // 0..15
    const int strip = w >> 1;     // 0..7
    const int half  = w & 1;      // 0..1
    const int lr = l & 15;
    const int lg = l >> 4;

    float bv[4];
#pragma unroll
    for (int nt = 0; nt < 4; ++nt) bv[nt] = b[half * 64 + nt * 16 + lr];

    f32x4 acc[4] = {};
    const int ar = strip * 16 + lr;
    const int abase = ar << 7;
    const int asw = (ar & 15) << 3;
#pragma unroll
    for (int kk = 0; kk < 4; ++kk) {
        const int k = kk * 32 + lg * 8;
        const bf16x8 af = *(const bf16x8*)&a_s[abase + (k ^ asw)];
#pragma unroll
        for (int nt = 0; nt < 4; ++nt) {
            const int br = half * 64 + nt * 16 + lr;
            const bf16x8 bf = *(const bf16x8*)&w_s[(br << 7) + (k ^ ((br & 15) << 3))];
            acc[nt] = __builtin_amdgcn_mfma_f32_16x16x32_bf16(af, bf, acc[nt], 0, 0, 0);
        }
    }

    // C/D: col = lane&15, row = (lane>>4)*4 + reg  (m89-verified)
#pragma unroll
    for (int nt = 0; nt < 4; ++nt) {
#pragma unroll
        for (int j = 0; j < 4; ++j) {
            const int row = tile + strip * 16 + lg * 4 + j;
            if (row < nN)
                out[(size_t)row * 128 + half * 64 + nt * 16 + lr] = acc[nt][j] + bv[nt];
        }
    }
}

// ============================================================================
// FALLBACK: atomic path (ws too small / nN too large for u16 packing)
// ============================================================================
__global__ void gcn_scatter(const int* __restrict__ edge,
                            const float* __restrict__ x,
                            float* __restrict__ agg,
                            float* __restrict__ deg, int nE, int nN) {
    const int lane  = threadIdx.x & 63;
    const int wave  = (blockIdx.x * blockDim.x + threadIdx.x) >> 6;
    const int nWave = (gridDim.x * blockDim.x) >> 6;
    for (int e = wave; e < nE; e += nWave) {
        int r = edge[e];
        int c = edge[nE + e];
        if ((unsigned)r >= (unsigned)nN || (unsigned)c >= (unsigned)nN) continue;
        const float2 v = ((const float2*)(x + (size_t)c * D_C))[lane];
        float* op = agg + (size_t)r * D_C + 2 * lane;
        atomicAdd(op, v.x);
        atomicAdd(op + 1, v.y);
        if (lane == 0) atomicAdd(deg + r, 1.0f);
    }
}

__global__ void gcn_mm(float* __restrict__ io, const float* __restrict__ deg,
                       const float* __restrict__ W, const float* __restrict__ b,
                       int nN) {
    __shared__ float a[D_C];
    const int c = threadIdx.x;
    const float bias = b[c];
    const float4* __restrict__ w4 = (const float4*)(W + (size_t)c * D_C);
    for (int r = blockIdx.x; r < nN; r += gridDim.x) {
        const float inv = 1.0f / deg[r];
        a[c] = io[(size_t)r * D_C + c] * inv;
        __syncthreads();
        float acc = bias;
        const float4* a4 = (const float4*)a;
#pragma unroll
        for (int k = 0; k < D_C / 4; ++k) {
            const float4 wv = w4[k];
            const float4 av = a4[k];
            acc = fmaf(wv.x, av.x, acc);
            acc = fmaf(wv.y, av.y, acc);
            acc = fmaf(wv.z, av.z, acc);
            acc = fmaf(wv.w, av.w, acc);
        }
        __syncthreads();
        io[(size_t)r * D_C + c] = acc;
    }
}

extern "C" void kernel_launch(void* const* d_in, const int* in_sizes, int n_in,
                              void* d_out, int out_size, void* d_ws, size_t ws_size,
                              hipStream_t stream) {
    const float* x    = (const float*)d_in[0];
    const int*   edge = (const int*)  d_in[1];
    const float* W    = (const float*)d_in[2];
    const float* b    = (const float*)d_in[3];

    const int nN = in_sizes[0] / D_C;   // 50000
    const int nE = in_sizes[1] / 2;     // 800000
    const int n8 = nN * D_C / 8;

    const int nBin  = (nN + (1 << BIN_SHIFT) - 1) >> BIN_SHIFT;         // 98
    const int nBlkA = (nE + BIN_CHUNK - 1) / BIN_CHUNK;                 // 391
    const size_t need = (size_t)nBin * nBlkA * SEG_W * sizeof(unsigned)
                      + (size_t)nN * D_C * sizeof(unsigned short);      // ~22.6 MB

    if (nN < 65536 && nBin <= 128 && ws_size >= need) {
        unsigned* seg = (unsigned*)d_ws;
        unsigned short* xb = (unsigned short*)(seg + (size_t)nBin * nBlkA * SEG_W);

        gcn_cvt <<<(n8 + 255) / 256, 256, 0, stream>>>(x, xb, n8);
        gcn_binA<<<nBlkA, 256, 0, stream>>>(edge, seg, nE, nN, nBin, nBlkA);
        const int nT = (nN + 127) / 128;                                // 391
        gcn_fused3<<<nT, 1024, 0, stream>>>(xb, seg, W, b,
                                            (float*)d_out, nN, nBlkA);
    } else {
        float* agg = (float*)d_out;
        float* deg = (float*)d_ws;
        hipMemsetAsync(agg, 0, (size_t)out_size * sizeof(float), stream);
        hipMemsetAsync(deg, 0, (size_t)nN * sizeof(float), stream);
        gcn_scatter<<<2048, 256, 0, stream>>>(edge, x, agg, deg, nE, nN);
        gcn_mm<<<nN, 128, 0, stream>>>(agg, deg, W, b, nN);
    }
}